// Round 5
// baseline (107.813 us; speedup 1.0000x reference)
//
#include <hip/hip_runtime.h>

#define NUM_K 64
#define CDIM 32
#define HW 16384          // 128*128
#define NPTS 1048576      // 64*128*128
#define NELEMD 33554432.0 // 64*32*128*128

// numpy pairwise sum of squares, n=32 contiguous: 8 accumulators + fixed tree.
// Products must round fp32 individually (contract off, plain mul).
__device__ __forceinline__ float np_sumsq32(const float* v) {
#pragma clang fp contract(off)
    float r[8];
    #pragma unroll
    for (int j = 0; j < 8; ++j) {
        float p0 = v[j] * v[j];
        float p1 = v[j + 8] * v[j + 8];
        float p2 = v[j + 16] * v[j + 16];
        float p3 = v[j + 24] * v[j + 24];
        r[j] = ((p0 + p1) + p2) + p3;
    }
    return ((r[0] + r[1]) + (r[2] + r[3])) + ((r[4] + r[5]) + (r[6] + r[7]));
}

// Prepass: B[k] = np.sum(emb*emb, axis=1), numpy fp32 order -> global scratch
// (read via s_load in the main loop).
__global__ void vq_prep(const float* __restrict__ emb, float* __restrict__ Bg) {
#pragma clang fp contract(off)
    int k = threadIdx.x;
    if (k < NUM_K) {
        float e[CDIM];
        #pragma unroll
        for (int c = 0; c < CDIM; ++c) e[c] = emb[k * CDIM + c];
        Bg[k] = np_sumsq32(e);
    }
}

// 2 points per thread: amortizes the per-k scalar codebook loads over 2x the
// FMA work and gives two independent FMA chains per k (in-wave ILP), attacking
// the ~68% stall fraction measured in round 4.
__global__ __launch_bounds__(256) void vq_main(const float* __restrict__ x,
                                               const float* __restrict__ emb,
                                               const float* __restrict__ Bg,
                                               float* __restrict__ outq,
                                               double* __restrict__ ws) {
#pragma clang fp contract(off)
    __shared__ float sET[CDIM][NUM_K];  // transposed codebook for the divergent gather
    __shared__ float sRed[4];

    const int t = threadIdx.x;
    // Conflict-free staging: thread i writes flat LDS addr i (bank i%32).
    #pragma unroll
    for (int i = t; i < NUM_K * CDIM; i += 256) {
        int c = i >> 6, k = i & 63;
        ((float*)sET)[i] = emb[k * CDIM + c];   // sET[c][k], flat = c*64+k = i
    }
    __syncthreads();

    const int p0 = blockIdx.x * 512 + t;       // block covers 512 consecutive points
    const int p1 = p0 + 256;
    const int b0 = p0 >> 14, b1 = p1 >> 14;    // 512 | 16384 -> never crosses an image
    const size_t base0 = (size_t)b0 * (CDIM * HW) + (p0 & (HW - 1));
    const size_t base1 = (size_t)b1 * (CDIM * HW) + (p1 & (HW - 1));
    const float* xp0 = x + base0;
    const float* xp1 = x + base1;

    // Issue all 64 loads up front (max MLP), coalesced across lanes.
    float xv0[CDIM], xv1[CDIM];
    #pragma unroll
    for (int c = 0; c < CDIM; ++c) xv0[c] = xp0[(size_t)c * HW];
    #pragma unroll
    for (int c = 0; c < CDIM; ++c) xv1[c] = xp1[(size_t)c * HW];

    const float A0 = np_sumsq32(xv0);
    const float A1 = np_sumsq32(xv1);

    // d_k = fp32( fp32(A + B_k) - 2*C_k ); C_k = ascending-c sequential fp32 FMA
    // chain; fmaf(-2,acc,t1) == t1-(acc+acc) bitwise. Strict < ascending k =
    // first-min (np.argmin). Bit-identical to the passing round-3/4 kernel.
    float best0 = 3.4028235e38f, best1 = 3.4028235e38f;
    int bi0 = 0, bi1 = 0;
    #pragma unroll 2
    for (int k = 0; k < NUM_K; ++k) {
        const float* __restrict__ ek = emb + k * CDIM;  // uniform -> s_load -> SGPR
        float a0 = 0.f, a1 = 0.f;
        #pragma unroll
        for (int c = 0; c < CDIM; ++c) {
            float e = ek[c];
            a0 = fmaf(xv0[c], e, a0);
            a1 = fmaf(xv1[c], e, a1);
        }
        float bk = Bg[k];
        float d0 = fmaf(-2.f, a0, A0 + bk);
        float d1 = fmaf(-2.f, a1, A1 + bk);
        if (d0 < best0) { best0 = d0; bi0 = k; }
        if (d1 < best1) { best1 = d1; bi1 = k; }
    }

    // Gather winners + nontemporal stores (outq never re-read: keep L3 for x).
    float* op0 = outq + base0;
    float* op1 = outq + base1;
    float lsum = 0.f;
    #pragma unroll
    for (int c = 0; c < CDIM; ++c) {
        float q0 = sET[c][bi0];
        float q1 = sET[c][bi1];
        __builtin_nontemporal_store(q0, &op0[(size_t)c * HW]);
        __builtin_nontemporal_store(q1, &op1[(size_t)c * HW]);
        float f0 = q0 - xv0[c];
        float f1 = q1 - xv1[c];
        lsum = fmaf(f0, f0, lsum);
        lsum = fmaf(f1, f1, lsum);
    }

    #pragma unroll
    for (int off = 32; off > 0; off >>= 1)
        lsum += __shfl_down(lsum, off, 64);
    const int wid = t >> 6;
    if ((t & 63) == 0) sRed[wid] = lsum;
    __syncthreads();
    if (t == 0) {
        double bs = (double)sRed[0] + (double)sRed[1] + (double)sRed[2] + (double)sRed[3];
        atomicAdd(ws, bs);
    }
}

__global__ void vq_finish(const double* __restrict__ ws, float* __restrict__ loss) {
    loss[0] = (float)(1.25 * ws[0] / NELEMD);
}

extern "C" void kernel_launch(void* const* d_in, const int* in_sizes, int n_in,
                              void* d_out, int out_size, void* d_ws, size_t ws_size,
                              hipStream_t stream) {
    const float* x = (const float*)d_in[0];
    const float* emb = (const float*)d_in[1];
    float* out = (float*)d_out;
    // ws layout: [0..7] double loss accumulator, [16..272) float B[64]
    double* acc = (double*)d_ws;
    float* Bg = (float*)((char*)d_ws + 16);

    hipMemsetAsync(d_ws, 0, sizeof(double), stream);  // zero accumulator every call
    vq_prep<<<1, 64, 0, stream>>>(emb, Bg);
    vq_main<<<NPTS / 512, 256, 0, stream>>>(x, emb, Bg, out + 1, acc);
    vq_finish<<<1, 1, 0, stream>>>(acc, out);
}